// Round 2
// baseline (157.966 us; speedup 1.0000x reference)
//
#include <hip/hip_runtime.h>
#include <stdint.h>

#define NT 4
#define PP 100
#define TT_BYTES (4ull * 100 * 100 * 1024)     // 40,960,000 B tT table in d_ws
#define C2B_DWORDS (NT * PP * 64)              // 25600 dwords = 102400 B (exact fit)

// tT layout per combo (tab,i0,i1), 1 KB, row-major [ab=16][s=32] bf16:
//   byte = ab*64 + s*2. MFMA A-frag for lane l is 16B at (l&15)*64 + (l>>4)*16
//   giving A[row=ab=l&15][k=8*(l>>4)+e] (contiguous-8 k mapping).
// c2b layout per (tab,i2), 256 B, [c=4][s=32] bf16: byte = c*64 + s*2.
//   B-frag: 16B at (col&3)*64 + (l>>4)*16 = B[k=8*(l>>4)+e][n=col&3].
//   Lanes col>=4 load a replica of col&3 (finite garbage in unused D cols).

typedef short bf16x8 __attribute__((ext_vector_type(8)));
typedef float f32x4  __attribute__((ext_vector_type(4)));

__device__ __forceinline__ uint32_t f2bf(float f) {
    union { float f; uint32_t u; } v; v.f = f;
    uint32_t u = v.u;
    return (u + 0x7fffu + ((u >> 16) & 1u)) >> 16;   // RNE to bf16
}

// ---------------- Phase 0: pack c2 as [tab][i2][c=4][s=32] bf16 ----------------
__global__ __launch_bounds__(256)
void c2pack_kernel(const float* __restrict__ c2g, uint32_t* __restrict__ c2p) {
    int t = blockIdx.x * 256 + threadIdx.x;       // combo*64 + c*16 + sg
    if (t >= C2B_DWORDS) return;
    int sg = t & 15, c = (t >> 4) & 3, combo = t >> 6;
    const float* src = c2g + (size_t)combo * 128; // c2 row is [s=32][c=4] f32
    c2p[t] = f2bf(src[(2 * sg) * 4 + c]) | (f2bf(src[(2 * sg + 1) * 4 + c]) << 16);
}

// ---------------- Phase 1: t[tab,i0,i1] = c0[tab,i0] @ c1[tab,i1] ----------------
// grid: 4 tab * 100 i1 * 7 chunks(16 i0) = 2800 blocks, 128 threads.
// thread (u 0..7, sg 0..15): 2 i0 (2u,2u+1), s-pair (2sg,2sg+1), all 16 ab.
// Store: per i0, 16 dwords at byte ab*64 + sg*4 (wave instr = 4x64B segments).
__global__ __launch_bounds__(128, 3)
void tt_phase1(const float* __restrict__ c0g, const float* __restrict__ c1g,
               unsigned short* __restrict__ tT) {
    __shared__ float c1s[32 * 128];   // [r][b*32+s]
    __shared__ float c0t[16 * 132];   // [i0l][r*4+a] (padded stride)

    int blk = blockIdx.x;
    int tab   = blk / 700;
    int rem   = blk % 700;
    int i1    = rem / 7;
    int chunk = rem % 7;
    int i0_base = chunk * 16;
    int tid = threadIdx.x;

    const float4* c1p = (const float4*)(c1g + (size_t)(tab * PP + i1) * 4096);
    float4* c1v = (float4*)c1s;
    #pragma unroll
    for (int it = 0; it < 8; ++it) c1v[tid + 128 * it] = c1p[tid + 128 * it];

    #pragma unroll
    for (int it = 0; it < 16; ++it) {
        int f = tid + 128 * it;          // 0..2047
        int i0l = f >> 7;
        int x   = f & 127;               // a*32 + r
        int a = x >> 5, r = x & 31;
        int i0 = i0_base + i0l; if (i0 > PP - 1) i0 = PP - 1;
        c0t[i0l * 132 + r * 4 + a] = c0g[(size_t)(tab * PP + i0) * 128 + x];
    }
    __syncthreads();

    int u  = tid >> 4;                   // 0..7
    int sg = tid & 15;

    float acc[2][2][16];                 // [i0 sel][e (s parity)][ab]
    #pragma unroll
    for (int ii = 0; ii < 2; ++ii)
        #pragma unroll
        for (int e = 0; e < 2; ++e)
            #pragma unroll
            for (int q = 0; q < 16; ++q) acc[ii][e][q] = 0.f;

    #pragma unroll 4
    for (int r = 0; r < 32; ++r) {
        float4 av0 = *(const float4*)&c0t[(2 * u) * 132 + r * 4];
        float4 av1 = *(const float4*)&c0t[(2 * u + 1) * 132 + r * 4];
        const float* a0 = (const float*)&av0;
        const float* a1 = (const float*)&av1;
        #pragma unroll
        for (int b = 0; b < 4; ++b) {
            float2 bv = *(const float2*)&c1s[r * 128 + b * 32 + 2 * sg];
            #pragma unroll
            for (int a = 0; a < 4; ++a) {
                acc[0][0][a * 4 + b] += a0[a] * bv.x;
                acc[0][1][a * 4 + b] += a0[a] * bv.y;
                acc[1][0][a * 4 + b] += a1[a] * bv.x;
                acc[1][1][a * 4 + b] += a1[a] * bv.y;
            }
        }
    }

    #pragma unroll
    for (int ii = 0; ii < 2; ++ii) {
        int i0 = i0_base + 2 * u + ii;
        if (i0 >= PP) continue;
        size_t combo = (size_t)tab * 10000 + (size_t)i0 * 100 + (size_t)i1;
        char* base = (char*)tT + combo * 1024 + (size_t)sg * 4;
        #pragma unroll
        for (int ab = 0; ab < 16; ++ab) {
            // dword at ab*64 + sg*4 packs bf16(s=2sg) lo, bf16(s=2sg+1) hi
            uint32_t w = f2bf(acc[ii][0][ab]) | (f2bf(acc[ii][1][ab]) << 16);
            *(uint32_t*)(base + ab * 64) = w;
        }
    }
}

// ---------------- Phase 2: K-concatenated MFMA over the bag ----------------
// 1 wave per bag, 4 waves/block. out_bag[16,4] = sum_j t_j[16,32] @ c2_j[32,4]
// = 16 chained v_mfma_f32_16x16x32_bf16 into one f32x4 accumulator.
// Lane l: A-frag row = l&15 (=ab), k-block = l>>4; D: col=l&15 (=c),
// row=(l>>4)*4+reg (=ab). All 16 A gathers issued up-front, fully coalesced
// (64 lanes x 16B = the combo's contiguous 1KB per load instruction).
__global__ __launch_bounds__(256, 4)
void tt_phase2(const int* __restrict__ indices, const int* __restrict__ offsets,
               const char* __restrict__ tT, const char* __restrict__ c2b,
               float* __restrict__ out, int bags_per_table, int B) {
    int lane = threadIdx.x & 63;
    int wv   = threadIdx.x >> 6;
    int bag  = blockIdx.x * 4 + wv;
    if (bag >= B) return;
    int col = lane & 15;
    int kq  = lane >> 4;
    int tab = bag / bags_per_table;
    int start = offsets[bag];

    // lane (col) owns lookup j = col; lanes 16..63 replicate so readlane works
    uint32_t idx = (uint32_t)indices[start + col];
    uint32_t i0 = idx / 10000u;
    uint32_t r1 = idx - i0 * 10000u;
    uint32_t i1 = r1 / 100u;
    uint32_t i2 = r1 - i1 * 100u;
    uint32_t tby = (((uint32_t)tab * 10000u + i0 * 100u + i1) << 10);  // *1024
    uint32_t cby = (((uint32_t)tab * 100u + i2) << 8);                 // *256

    int aoff = col * 64 + kq * 16;        // A fragment byte offset (row=col)
    int boff = (col & 3) * 64 + kq * 16;  // B fragment byte offset (n=col&3)

    bf16x8 A[16];
    #pragma unroll
    for (int j = 0; j < 16; ++j) {
        uint32_t tb = (uint32_t)__builtin_amdgcn_readlane((int)tby, j);
        A[j] = *(const bf16x8*)(tT + tb + aoff);
    }

    f32x4 acc = {0.f, 0.f, 0.f, 0.f};
    #pragma unroll
    for (int j = 0; j < 16; ++j) {
        uint32_t cb = (uint32_t)__builtin_amdgcn_readlane((int)cby, j);
        const bf16x8 Bv = *(const bf16x8*)(c2b + cb + boff);
        acc = __builtin_amdgcn_mfma_f32_16x16x32_bf16(A[j], Bv, acc, 0, 0, 0);
    }

    // D frag: lane holds out[d] for d = kq*16 + q*4 + col, q=0..3 (col<4 only)
    if (col < 4) {
        float* o = out + (size_t)bag * 64 + kq * 16 + col;
        o[0]  = acc[0];
        o[4]  = acc[1];
        o[8]  = acc[2];
        o[12] = acc[3];
    }
}

extern "C" void kernel_launch(void* const* d_in, const int* in_sizes, int n_in,
                              void* d_out, int out_size, void* d_ws, size_t ws_size,
                              hipStream_t stream) {
    const int*   indices = (const int*)d_in[0];
    const int*   offsets = (const int*)d_in[1];
    const float* c0      = (const float*)d_in[2];
    const float* c1      = (const float*)d_in[3];
    const float* c2      = (const float*)d_in[4];
    float* out = (float*)d_out;

    int B = in_sizes[1] - 1;              // 32768 bags
    int bags_per_table = B / NT;          // 8192

    unsigned short* tT  = (unsigned short*)d_ws;
    uint32_t*       c2p = (uint32_t*)((char*)d_ws + TT_BYTES);

    c2pack_kernel<<<dim3((C2B_DWORDS + 255) / 256), dim3(256), 0, stream>>>(c2, c2p);
    tt_phase1<<<dim3(NT * PP * 7), dim3(128), 0, stream>>>(c0, c1, tT);
    tt_phase2<<<dim3((B + 3) / 4), dim3(256), 0, stream>>>(indices, offsets,
                                                           (const char*)tT,
                                                           (const char*)c2p, out,
                                                           bags_per_table, B);
}

// Round 3
// 154.176 us; speedup vs baseline: 1.0246x; 1.0246x over previous
//
#include <hip/hip_runtime.h>
#include <stdint.h>

#define NT 4
#define PP 100
#define TT_BYTES (4ull * 100 * 100 * 1024)     // 40,960,000 B tT table in d_ws
#define C2B_DWORDS (NT * PP * 64)              // 25600 dwords = 102400 B (exact fit)

// tT layout per combo (tab,i0,i1), 1 KB, row-major [ab=16][s=32] bf16:
//   byte = ab*64 + s*2. MFMA A-frag for lane l is 16B at (l&15)*64 + (l>>4)*16.
// c2b layout per (tab,i2), 256 B, [c=4][s=32] bf16: byte = c*64 + s*2.
//   B-frag: 16B at (col&3)*64 + (l>>4)*16. Lanes col>=4 replicate col&3
//   (finite garbage lands in unused D cols 4..15).

typedef short bf16x8 __attribute__((ext_vector_type(8)));
typedef float f32x4  __attribute__((ext_vector_type(4)));
typedef float f32x2  __attribute__((ext_vector_type(2)));

__device__ __forceinline__ uint32_t f2bf(float f) {
    union { float f; uint32_t u; } v; v.f = f;
    uint32_t u = v.u;
    return (u + 0x7fffu + ((u >> 16) & 1u)) >> 16;   // RNE to bf16
}

// ---------------- Phase 0: pack c2 as [tab][i2][c=4][s=32] bf16 ----------------
__global__ __launch_bounds__(256)
void c2pack_kernel(const float* __restrict__ c2g, uint32_t* __restrict__ c2p) {
    int t = blockIdx.x * 256 + threadIdx.x;       // combo*64 + c*16 + sg
    if (t >= C2B_DWORDS) return;
    int sg = t & 15, c = (t >> 4) & 3, combo = t >> 6;
    const float* src = c2g + (size_t)combo * 128; // c2 row is [s=32][c=4] f32
    c2p[t] = f2bf(src[(2 * sg) * 4 + c]) | (f2bf(src[(2 * sg + 1) * 4 + c]) << 16);
}

// ---------------- Phase 1: t[tab,i0,i1] = c0[tab,i0] @ c1[tab,i1] ----------------
// grid: 4 tab * 100 i1 * 7 chunks(16 i0) = 2800 blocks, 128 threads.
// thread (u 0..7, sg 0..15): 2 i0 (2u,2u+1), s-pair (2sg,2sg+1), all 16 ab.
// Inner loop uses f32x2 accumulators over the s-parity pair -> v_pk_fma_f32
// (packed f32 runs at 2x scalar v_fmac_f32 rate; numerics identical).
__global__ __launch_bounds__(128, 3)
void tt_phase1(const float* __restrict__ c0g, const float* __restrict__ c1g,
               unsigned short* __restrict__ tT) {
    __shared__ float c1s[32 * 128];   // [r][b*32+s]
    __shared__ float c0t[16 * 132];   // [i0l][r*4+a] (padded stride)

    int blk = blockIdx.x;
    int tab   = blk / 700;
    int rem   = blk % 700;
    int i1    = rem / 7;
    int chunk = rem % 7;
    int i0_base = chunk * 16;
    int tid = threadIdx.x;

    const float4* c1p = (const float4*)(c1g + (size_t)(tab * PP + i1) * 4096);
    float4* c1v = (float4*)c1s;
    #pragma unroll
    for (int it = 0; it < 8; ++it) c1v[tid + 128 * it] = c1p[tid + 128 * it];

    #pragma unroll
    for (int it = 0; it < 16; ++it) {
        int f = tid + 128 * it;          // 0..2047
        int i0l = f >> 7;
        int x   = f & 127;               // a*32 + r
        int a = x >> 5, r = x & 31;
        int i0 = i0_base + i0l; if (i0 > PP - 1) i0 = PP - 1;
        c0t[i0l * 132 + r * 4 + a] = c0g[(size_t)(tab * PP + i0) * 128 + x];
    }
    __syncthreads();

    int u  = tid >> 4;                   // 0..7
    int sg = tid & 15;

    f32x2 acc[2][16];                    // [i0 sel][ab], lanes = s parity (e)
    #pragma unroll
    for (int ii = 0; ii < 2; ++ii)
        #pragma unroll
        for (int q = 0; q < 16; ++q) acc[ii][q] = (f32x2){0.f, 0.f};

    #pragma unroll 4
    for (int r = 0; r < 32; ++r) {
        float4 av0 = *(const float4*)&c0t[(2 * u) * 132 + r * 4];
        float4 av1 = *(const float4*)&c0t[(2 * u + 1) * 132 + r * 4];
        const float* a0 = (const float*)&av0;
        const float* a1 = (const float*)&av1;
        #pragma unroll
        for (int b = 0; b < 4; ++b) {
            f32x2 bv = *(const f32x2*)&c1s[r * 128 + b * 32 + 2 * sg];
            #pragma unroll
            for (int a = 0; a < 4; ++a) {
                acc[0][a * 4 + b] += (f32x2){a0[a], a0[a]} * bv;  // v_pk_fma_f32
                acc[1][a * 4 + b] += (f32x2){a1[a], a1[a]} * bv;
            }
        }
    }

    #pragma unroll
    for (int ii = 0; ii < 2; ++ii) {
        int i0 = i0_base + 2 * u + ii;
        if (i0 >= PP) continue;
        size_t combo = (size_t)tab * 10000 + (size_t)i0 * 100 + (size_t)i1;
        char* base = (char*)tT + combo * 1024 + (size_t)sg * 4;
        #pragma unroll
        for (int ab = 0; ab < 16; ++ab) {
            // dword at ab*64 + sg*4 packs bf16(s=2sg) lo, bf16(s=2sg+1) hi
            uint32_t w = f2bf(acc[ii][ab].x) | (f2bf(acc[ii][ab].y) << 16);
            *(uint32_t*)(base + ab * 64) = w;
        }
    }
}

// ---------------- Phase 2: bag per BLOCK, 4 waves x 4 lookups, LDS reduce ----------------
// Rationale: per-wave register budget stays ~50 VGPR (4 A-frags + 4 B-frags),
// so ALL 8 gathers per wave issue before the MFMA chain; a CU at ~6 resident
// blocks has ~96 independent wave-gathers outstanding (vs ~10 in the rolled
// 16-lookup/wave version that the compiler serialized at VGPR_Count=36).
__global__ __launch_bounds__(256, 6)
void tt_phase2(const int* __restrict__ indices, const int* __restrict__ offsets,
               const char* __restrict__ tT, const char* __restrict__ c2b,
               float* __restrict__ out, int bags_per_table, int B) {
    __shared__ float red[4][64];
    int lane = threadIdx.x & 63;
    int wv   = threadIdx.x >> 6;         // 0..3: this wave's 4 lookups
    int bag  = blockIdx.x;
    int col = lane & 15;
    int kq  = lane >> 4;
    int tab = bag / bags_per_table;
    int start = offsets[bag];

    // lane col owns lookup jj = col&3 of this wave; lanes replicate so
    // readlane(.., jj) (jj<4) picks lane jj's address.
    uint32_t idx = (uint32_t)indices[start + wv * 4 + (col & 3)];
    uint32_t i0 = idx / 10000u;
    uint32_t r1 = idx - i0 * 10000u;
    uint32_t i1 = r1 / 100u;
    uint32_t i2 = r1 - i1 * 100u;
    uint32_t tby = (((uint32_t)tab * 10000u + i0 * 100u + i1) << 10);  // *1024
    uint32_t cby = (((uint32_t)tab * 100u + i2) << 8);                 // *256

    int aoff = col * 64 + kq * 16;        // A fragment byte offset (row=col)
    int boff = (col & 3) * 64 + kq * 16;  // B fragment byte offset (n=col&3)

    bf16x8 A[4], Bv[4];
    #pragma unroll
    for (int jj = 0; jj < 4; ++jj) {
        uint32_t tb = (uint32_t)__builtin_amdgcn_readlane((int)tby, jj);
        uint32_t cb = (uint32_t)__builtin_amdgcn_readlane((int)cby, jj);
        A[jj]  = *(const bf16x8*)(tT  + tb + aoff);
        Bv[jj] = *(const bf16x8*)(c2b + cb + boff);
    }

    f32x4 acc = {0.f, 0.f, 0.f, 0.f};
    #pragma unroll
    for (int jj = 0; jj < 4; ++jj)
        acc = __builtin_amdgcn_mfma_f32_16x16x32_bf16(A[jj], Bv[jj], acc, 0, 0, 0);

    // D frag: lane (col<4) holds out[d], d = kq*16 + q*4 + col
    if (col < 4) {
        #pragma unroll
        for (int q = 0; q < 4; ++q)
            red[wv][kq * 16 + q * 4 + col] = acc[q];
    }
    __syncthreads();
    if (wv == 0) {
        float s = red[0][lane] + red[1][lane] + red[2][lane] + red[3][lane];
        out[(size_t)bag * 64 + lane] = s;
    }
}

extern "C" void kernel_launch(void* const* d_in, const int* in_sizes, int n_in,
                              void* d_out, int out_size, void* d_ws, size_t ws_size,
                              hipStream_t stream) {
    const int*   indices = (const int*)d_in[0];
    const int*   offsets = (const int*)d_in[1];
    const float* c0      = (const float*)d_in[2];
    const float* c1      = (const float*)d_in[3];
    const float* c2      = (const float*)d_in[4];
    float* out = (float*)d_out;

    int B = in_sizes[1] - 1;              // 32768 bags
    int bags_per_table = B / NT;          // 8192

    unsigned short* tT  = (unsigned short*)d_ws;
    uint32_t*       c2p = (uint32_t*)((char*)d_ws + TT_BYTES);

    c2pack_kernel<<<dim3((C2B_DWORDS + 255) / 256), dim3(256), 0, stream>>>(c2, c2p);
    tt_phase1<<<dim3(NT * PP * 7), dim3(128), 0, stream>>>(c0, c1, tT);
    tt_phase2<<<dim3(B), dim3(256), 0, stream>>>(indices, offsets,
                                                 (const char*)tT,
                                                 (const char*)c2p, out,
                                                 bags_per_table, B);
}

// Round 6
// 144.167 us; speedup vs baseline: 1.0957x; 1.0694x over previous
//
#include <hip/hip_runtime.h>
#include <stdint.h>

#define NT 4
#define PP 100
#define TT_BYTES (4ull * 100 * 100 * 1024)     // 40,960,000 B tT table in d_ws
#define C2B_DWORDS (NT * PP * 64)              // 25600 dwords = 102400 B (exact fit)

// tT layout per combo (tab,i0,i1), 1 KB, row-major [ab=16][s=32] bf16:
//   byte = ab*64 + s*2. MFMA A-frag for lane l is 16B at (l&15)*64 + (l>>4)*16.
// c2b layout per (tab,i2), 256 B, [c=4][s=32] bf16: byte = c*64 + s*2.

typedef short bf16x8 __attribute__((ext_vector_type(8)));
typedef float f32x4  __attribute__((ext_vector_type(4)));

__device__ __forceinline__ uint32_t f2bf(float f) {
    union { float f; uint32_t u; } v; v.f = f;
    uint32_t u = v.u;
    return (u + 0x7fffu + ((u >> 16) & 1u)) >> 16;   // RNE to bf16
}

// ---------------- Phase 1 (MFMA) + merged c2pack ----------------
// Blocks 0..1599:  T[(i0,a)][(b,s)] = c0v[M x 32] @ c1v[32 x 128] per
//   (tab, i1, 25-i0 chunk). M=100 (pad 112), N=128, K=32. 7x8 tiles of
//   16x16x32 bf16 MFMA, 4 waves (wave w owns nt = 2w, 2w+1).
//   A,B staged in LDS bf16 [row][k] 64B-stride with dword-slot XOR swizzle
//   (slot ^ ((row&3)<<2)) breaking the stride-16-bank pattern on ds_read_b128.
//   A pad rows (100..111) zero-initialized (defensive: no uninit MFMA input).
//   D staged in LDS bf16 [100][128]; copyout 16B-contiguous on both sides.
// Blocks 1600..1699: pack c2 as [tab][i2][c=4][s=32] bf16 (was c2pack_kernel).
__global__ __launch_bounds__(256)
void tt_phase1(const float* __restrict__ c0g, const float* __restrict__ c1g,
               unsigned short* __restrict__ tT,
               const float* __restrict__ c2g, uint32_t* __restrict__ c2p) {
    __shared__ uint32_t       A_l[112 * 16];     // [row][kd] kd=k/2, swizzled
    __shared__ uint32_t       B_l[128 * 16];     // [n][rp]  rp=r/2, swizzled
    __shared__ unsigned short D_l[100 * 128];    // [Mrow][n] bf16

    int blk = blockIdx.x;                 // 1600 GEMM blocks + 100 pack blocks
    int tid = threadIdx.x;

    if (blk >= 1600) {                    // ---- c2pack path (whole block) ----
        int t = (blk - 1600) * 256 + tid; // combo*64 + c*16 + sg
        if (t < C2B_DWORDS) {
            int sg = t & 15, c = (t >> 4) & 3, combo = t >> 6;
            const float* src = c2g + (size_t)combo * 128;  // [s=32][c=4] f32
            c2p[t] = f2bf(src[(2 * sg) * 4 + c]) | (f2bf(src[(2 * sg + 1) * 4 + c]) << 16);
        }
        return;
    }

    int tab = blk / 400;
    int rem = blk % 400;
    int i1  = rem >> 2;
    int ch  = rem & 3;                    // i0 = ch*25 + i0l, i0l 0..24

    // --- zero A pad rows 100..111 (dwords 1600..1791) ---
    if (tid < 192) A_l[1600 + tid] = 0u;

    // --- stage A: 25 i0 x 128 f32 = 1600 float2, contiguous ---
    const float2* a2 = (const float2*)(c0g + (size_t)tab * 12800 + (size_t)ch * 3200);
    #pragma unroll
    for (int it = 0; it < 7; ++it) {
        int d = tid + it * 256;
        if (d < 1600) {
            float2 v = a2[d];
            int row = d >> 4, kd = d & 15;
            A_l[row * 16 + (kd ^ ((row & 3) << 2))] = f2bf(v.x) | (f2bf(v.y) << 16);
        }
    }
    // --- stage B (transpose): c1 row 4096 f32 -> [n][rp] packed pairs ---
    const float* c1row = c1g + ((size_t)tab * PP + i1) * 4096;
    #pragma unroll
    for (int it = 0; it < 8; ++it) {
        int j = tid + it * 256;           // j < 2048: n = j&127, rp = j>>7
        int n = j & 127, rp = j >> 7;
        float e = c1row[(2 * rp) * 128 + n];
        float o = c1row[(2 * rp + 1) * 128 + n];
        B_l[n * 16 + (rp ^ ((n & 3) << 2))] = f2bf(e) | (f2bf(o) << 16);
    }
    __syncthreads();

    int lane = tid & 63, wv = tid >> 6;
    int col = lane & 15, kq = lane >> 4;

    #pragma unroll
    for (int mt = 0; mt < 7; ++mt) {
        #pragma unroll
        for (int ntl = 0; ntl < 2; ++ntl) {
            int nt = wv * 2 + ntl;
            int arow = mt * 16 + col;
            int bn   = nt * 16 + col;
            bf16x8 af = *(const bf16x8*)&A_l[arow * 16 + ((kq ^ (arow & 3)) << 2)];
            bf16x8 bf = *(const bf16x8*)&B_l[bn   * 16 + ((kq ^ (bn   & 3)) << 2)];
            f32x4 acc = {0.f, 0.f, 0.f, 0.f};
            acc = __builtin_amdgcn_mfma_f32_16x16x32_bf16(af, bf, acc, 0, 0, 0);
            #pragma unroll
            for (int q = 0; q < 4; ++q) {
                int Drow = mt * 16 + kq * 4 + q;     // D row depends only on A row
                if (Drow < 100)
                    D_l[Drow * 128 + nt * 16 + col] = (unsigned short)f2bf(acc[q]);
            }
        }
    }
    __syncthreads();

    // --- copyout: 1600 16B chunks; 16B-contiguous in both D_l and tT ---
    #pragma unroll
    for (int it = 0; it < 7; ++it) {
        int c = tid + it * 256;
        if (c < 1600) {
            int Drow = c >> 4, w = c & 15;
            int i0l = Drow >> 2, a = Drow & 3;
            int b = w >> 2, so = w & 3;
            int i0 = ch * 25 + i0l;
            size_t combo = (size_t)tab * 10000 + (size_t)i0 * 100 + (size_t)i1;
            char* dst = (char*)tT + combo * 1024 + (size_t)(a * 4 + b) * 64 + (size_t)so * 16;
            *(uint4*)dst = *(const uint4*)&D_l[Drow * 128 + w * 8];
        }
    }
}

// ---------------- Phase 2: bag per BLOCK, 4 waves x 4 lookups, LDS reduce ----------------
// (byte-identical to round 3 — control: 65.7 us, FETCH ~178 MB)
__global__ __launch_bounds__(256, 6)
void tt_phase2(const int* __restrict__ indices, const int* __restrict__ offsets,
               const char* __restrict__ tT, const char* __restrict__ c2b,
               float* __restrict__ out, int bags_per_table, int B) {
    __shared__ float red[4][64];
    int lane = threadIdx.x & 63;
    int wv   = threadIdx.x >> 6;         // 0..3: this wave's 4 lookups
    int bag  = blockIdx.x;
    int col = lane & 15;
    int kq  = lane >> 4;
    int tab = bag / bags_per_table;
    int start = offsets[bag];

    uint32_t idx = (uint32_t)indices[start + wv * 4 + (col & 3)];
    uint32_t i0 = idx / 10000u;
    uint32_t r1 = idx - i0 * 10000u;
    uint32_t i1 = r1 / 100u;
    uint32_t i2 = r1 - i1 * 100u;
    uint32_t tby = (((uint32_t)tab * 10000u + i0 * 100u + i1) << 10);  // *1024
    uint32_t cby = (((uint32_t)tab * 100u + i2) << 8);                 // *256

    int aoff = col * 64 + kq * 16;        // A fragment byte offset (row=col)
    int boff = (col & 3) * 64 + kq * 16;  // B fragment byte offset (n=col&3)

    bf16x8 A[4], Bv[4];
    #pragma unroll
    for (int jj = 0; jj < 4; ++jj) {
        uint32_t tb = (uint32_t)__builtin_amdgcn_readlane((int)tby, jj);
        uint32_t cb = (uint32_t)__builtin_amdgcn_readlane((int)cby, jj);
        A[jj]  = *(const bf16x8*)(tT  + tb + aoff);
        Bv[jj] = *(const bf16x8*)(c2b + cb + boff);
    }

    f32x4 acc = {0.f, 0.f, 0.f, 0.f};
    #pragma unroll
    for (int jj = 0; jj < 4; ++jj)
        acc = __builtin_amdgcn_mfma_f32_16x16x32_bf16(A[jj], Bv[jj], acc, 0, 0, 0);

    if (col < 4) {
        #pragma unroll
        for (int q = 0; q < 4; ++q)
            red[wv][kq * 16 + q * 4 + col] = acc[q];
    }
    __syncthreads();
    if (wv == 0) {
        float s = red[0][lane] + red[1][lane] + red[2][lane] + red[3][lane];
        out[(size_t)bag * 64 + lane] = s;
    }
}

extern "C" void kernel_launch(void* const* d_in, const int* in_sizes, int n_in,
                              void* d_out, int out_size, void* d_ws, size_t ws_size,
                              hipStream_t stream) {
    const int*   indices = (const int*)d_in[0];
    const int*   offsets = (const int*)d_in[1];
    const float* c0      = (const float*)d_in[2];
    const float* c1      = (const float*)d_in[3];
    const float* c2      = (const float*)d_in[4];
    float* out = (float*)d_out;

    int B = in_sizes[1] - 1;              // 32768 bags
    int bags_per_table = B / NT;          // 8192

    unsigned short* tT  = (unsigned short*)d_ws;
    uint32_t*       c2p = (uint32_t*)((char*)d_ws + TT_BYTES);

    tt_phase1<<<dim3(1700), dim3(256), 0, stream>>>(c0, c1, tT, c2, c2p);
    tt_phase2<<<dim3(B), dim3(256), 0, stream>>>(indices, offsets,
                                                 (const char*)tT,
                                                 (const char*)c2p, out,
                                                 bags_per_table, B);
}